// Round 1
// baseline (566.482 us; speedup 1.0000x reference)
//
#include <hip/hip_runtime.h>

#define NN 50000
#define NE 800000

static __device__ __forceinline__ float lrelu(float x) { return x > 0.f ? x : 0.2f * x; }

// ---------------- edge-index dtype detection (int32 vs int64) ----------------
__global__ void detect_i64_kernel(const unsigned* __restrict__ ei, int* __restrict__ flag) {
  if (threadIdx.x == 0 && blockIdx.x == 0) {
    int is64 = 1;
    for (int i = 0; i < 64; ++i)
      if (ei[2 * i + 1] != 0u) { is64 = 0; break; }
    *flag = is64;
  }
}

static __device__ __forceinline__ int edge_at(const void* ei, int is64, long long idx) {
  if (is64) return (int)((const long long*)ei)[idx];
  return ((const int*)ei)[idx];
}

// ---------------- CSR build ----------------
__global__ void count_kernel(const void* __restrict__ ei, const int* __restrict__ flag,
                             int* __restrict__ counts) {
  int e = blockIdx.x * blockDim.x + threadIdx.x;
  if (e >= NE) return;
  int is64 = *flag;
  int d = edge_at(ei, is64, (long long)NE + e);
  atomicAdd(&counts[d], 1);
}

__global__ void scan_kernel(const int* __restrict__ counts, int* __restrict__ rs) {
  __shared__ int wsum[16];
  __shared__ int carry;
  const int tid = threadIdx.x;
  const int lane = tid & 63, wv = tid >> 6;
  if (tid == 0) { carry = 0; rs[0] = 0; }
  __syncthreads();
  for (int base = 0; base < NN; base += 1024) {
    int i = base + tid;
    int v = (i < NN) ? counts[i] : 0;
    #pragma unroll
    for (int off = 1; off < 64; off <<= 1) {
      int t = __shfl_up(v, off);
      if (lane >= off) v += t;
    }
    if (lane == 63) wsum[wv] = v;
    __syncthreads();
    if (tid == 0) {
      int run = 0;
      #pragma unroll
      for (int j = 0; j < 16; ++j) { run += wsum[j]; wsum[j] = run; }
    }
    __syncthreads();
    int add = carry + (wv ? wsum[wv - 1] : 0);
    if (i < NN) rs[i + 1] = add + v;
    __syncthreads();
    if (tid == 0) carry += wsum[15];
    __syncthreads();
  }
}

__global__ void scatter_kernel(const void* __restrict__ ei, const int* __restrict__ flag,
                               const int* __restrict__ rs, int* __restrict__ cursor,
                               int* __restrict__ ssrc) {
  int e = blockIdx.x * blockDim.x + threadIdx.x;
  if (e >= NE) return;
  int is64 = *flag;
  int s = edge_at(ei, is64, e);
  int d = edge_at(ei, is64, (long long)NE + e);
  int p = atomicAdd(&cursor[d], 1);
  ssrc[rs[d] + p] = s;
}

// ---------------- fp32 tiled GEMM: C[M,N] = A[M,K] @ B[K,N] ----------------
// BM=64, BK=16, 256 threads, each computes 4x4.  N % BN == 0, K % 16 == 0.
template<int BN>
__global__ __launch_bounds__(256) void gemm_f32(const float* __restrict__ A,
                                                const float* __restrict__ B,
                                                float* __restrict__ C,
                                                int M, int N, int K) {
  constexpr int BM = 64, BK = 16;
  __shared__ float As[BK][BM + 4];
  __shared__ float Bs[BK][BN];
  const int tid = threadIdx.x;
  const int tx = tid & 15, ty = tid >> 4;
  const int arow = tid >> 2, acol = (tid & 3) << 2;
  const int brow = tid >> 4, bcol = (tid & 15) << 2;
  const int grow = blockIdx.y * BM + arow;
  const int gcolb = blockIdx.x * BN;
  float acc[4][4] = {};
  for (int k0 = 0; k0 < K; k0 += BK) {
    float4 av = make_float4(0.f, 0.f, 0.f, 0.f);
    if (grow < M) av = *(const float4*)&A[(size_t)grow * K + k0 + acol];
    As[acol + 0][arow] = av.x;
    As[acol + 1][arow] = av.y;
    As[acol + 2][arow] = av.z;
    As[acol + 3][arow] = av.w;
    *(float4*)&Bs[brow][bcol] = *(const float4*)&B[(size_t)(k0 + brow) * N + gcolb + bcol];
    __syncthreads();
    #pragma unroll
    for (int kk = 0; kk < BK; ++kk) {
      float a0 = As[kk][ty * 4 + 0], a1 = As[kk][ty * 4 + 1],
            a2 = As[kk][ty * 4 + 2], a3 = As[kk][ty * 4 + 3];
      float b0 = Bs[kk][tx * 4 + 0], b1 = Bs[kk][tx * 4 + 1],
            b2 = Bs[kk][tx * 4 + 2], b3 = Bs[kk][tx * 4 + 3];
      acc[0][0] += a0 * b0; acc[0][1] += a0 * b1; acc[0][2] += a0 * b2; acc[0][3] += a0 * b3;
      acc[1][0] += a1 * b0; acc[1][1] += a1 * b1; acc[1][2] += a1 * b2; acc[1][3] += a1 * b3;
      acc[2][0] += a2 * b0; acc[2][1] += a2 * b1; acc[2][2] += a2 * b2; acc[2][3] += a2 * b3;
      acc[3][0] += a3 * b0; acc[3][1] += a3 * b1; acc[3][2] += a3 * b2; acc[3][3] += a3 * b3;
    }
    __syncthreads();
  }
  #pragma unroll
  for (int i = 0; i < 4; ++i) {
    int r = blockIdx.y * BM + ty * 4 + i;
    if (r < M) {
      float4 o = make_float4(acc[i][0], acc[i][1], acc[i][2], acc[i][3]);
      *(float4*)&C[(size_t)r * N + gcolb + tx * 4] = o;
    }
  }
}

// ---------------- per-(node,head) attention coefficients ----------------
template<int C>
__global__ void alpha_kernel(const float* __restrict__ h, const float* __restrict__ aws,
                             const float* __restrict__ awd, float* __restrict__ os,
                             float* __restrict__ od) {
  int i = blockIdx.x * blockDim.x + threadIdx.x;
  if (i >= NN * 8) return;
  int node = i >> 3, head = i & 7;
  const float* hp = h + (size_t)node * (8 * C) + head * C;
  const float* pws = aws + head * C;
  const float* pwd = awd + head * C;
  float s = 0.f, d = 0.f;
  #pragma unroll
  for (int c = 0; c < C; ++c) { float v = hp[c]; s += v * pws[c]; d += v * pwd[c]; }
  os[i] = s; od[i] = d;
}

// ---------------- layer-1 aggregation: softmax-by-dst + weighted sum + bias + ELU ----------------
// one wave per node; 256 channels -> 4 per lane (float4); head = lane>>3 in pass 2
__global__ __launch_bounds__(256) void agg1_kernel(const float* __restrict__ h,
    const float* __restrict__ as, const float* __restrict__ ad,
    const int* __restrict__ rs, const int* __restrict__ ssrc,
    const float* __restrict__ bias, float* __restrict__ out) {
  const int wid = (blockIdx.x * blockDim.x + threadIdx.x) >> 6;
  const int lane = threadIdx.x & 63;
  if (wid >= NN) return;
  const int node = wid;
  const int beg = rs[node], end = rs[node + 1];
  // pass 1: per-head max; head = lane&7, edge-slot = lane>>3 (8 edges in parallel)
  const int hA = lane & 7;
  const float advA = ad[node * 8 + hA];
  float m = lrelu(as[node * 8 + hA] + advA);   // self loop
  for (int it = beg + (lane >> 3); it < end; it += 8) {
    int s = ssrc[it];
    m = fmaxf(m, lrelu(as[s * 8 + hA] + advA));
  }
  m = fmaxf(m, __shfl_xor(m, 8));
  m = fmaxf(m, __shfl_xor(m, 16));
  m = fmaxf(m, __shfl_xor(m, 32));
  // pass 2: head = lane>>3, channels 4*lane .. 4*lane+3
  const int hd = lane >> 3;
  const float mh = __shfl(m, hd);              // lane 'hd' holds head hd's max
  const float advh = ad[node * 8 + hd];
  float denom;
  float4 acc;
  {
    float p = __expf(lrelu(as[node * 8 + hd] + advh) - mh);   // self loop
    float4 hv = *(const float4*)&h[(size_t)node * 256 + lane * 4];
    acc.x = p * hv.x; acc.y = p * hv.y; acc.z = p * hv.z; acc.w = p * hv.w;
    denom = p;
  }
  for (int it = beg; it < end; ++it) {
    int s = ssrc[it];
    float p = __expf(lrelu(as[s * 8 + hd] + advh) - mh);
    float4 hv = *(const float4*)&h[(size_t)s * 256 + lane * 4];
    acc.x += p * hv.x; acc.y += p * hv.y; acc.z += p * hv.z; acc.w += p * hv.w;
    denom += p;
  }
  const float inv = 1.f / (denom + 1e-16f);
  const float4 bv = *(const float4*)&bias[lane * 4];
  float4 o;
  o.x = acc.x * inv + bv.x; o.y = acc.y * inv + bv.y;
  o.z = acc.z * inv + bv.z; o.w = acc.w * inv + bv.w;
  o.x = o.x > 0.f ? o.x : __expf(o.x) - 1.f;
  o.y = o.y > 0.f ? o.y : __expf(o.y) - 1.f;
  o.z = o.z > 0.f ? o.z : __expf(o.z) - 1.f;
  o.w = o.w > 0.f ? o.w : __expf(o.w) - 1.f;
  *(float4*)&out[(size_t)node * 256 + lane * 4] = o;
}

// ---------------- layer-2 aggregation + bias + log_softmax ----------------
// one wave per node; 128 channels -> 2 per lane (float2); head = lane>>3
__global__ __launch_bounds__(256) void agg2_kernel(const float* __restrict__ h,
    const float* __restrict__ as, const float* __restrict__ ad,
    const int* __restrict__ rs, const int* __restrict__ ssrc,
    const float* __restrict__ bias, float* __restrict__ out) {
  const int wid = (blockIdx.x * blockDim.x + threadIdx.x) >> 6;
  const int lane = threadIdx.x & 63;
  if (wid >= NN) return;
  const int node = wid;
  const int beg = rs[node], end = rs[node + 1];
  const int hA = lane & 7;
  const float advA = ad[node * 8 + hA];
  float m = lrelu(as[node * 8 + hA] + advA);   // self loop
  for (int it = beg + (lane >> 3); it < end; it += 8) {
    int s = ssrc[it];
    m = fmaxf(m, lrelu(as[s * 8 + hA] + advA));
  }
  m = fmaxf(m, __shfl_xor(m, 8));
  m = fmaxf(m, __shfl_xor(m, 16));
  m = fmaxf(m, __shfl_xor(m, 32));
  const int hd = lane >> 3;
  const float mh = __shfl(m, hd);
  const float advh = ad[node * 8 + hd];
  float denom;
  float2 acc;
  {
    float p = __expf(lrelu(as[node * 8 + hd] + advh) - mh);   // self loop
    float2 hv = *(const float2*)&h[(size_t)node * 128 + lane * 2];
    acc.x = p * hv.x; acc.y = p * hv.y;
    denom = p;
  }
  for (int it = beg; it < end; ++it) {
    int s = ssrc[it];
    float p = __expf(lrelu(as[s * 8 + hd] + advh) - mh);
    float2 hv = *(const float2*)&h[(size_t)s * 128 + lane * 2];
    acc.x += p * hv.x; acc.y += p * hv.y;
    denom += p;
  }
  const float inv = 1.f / (denom + 1e-16f);
  float v0 = acc.x * inv + bias[lane * 2 + 0];
  float v1 = acc.y * inv + bias[lane * 2 + 1];
  // log_softmax over the 128-wide row (distributed 2/lane across the wave)
  float mx = fmaxf(v0, v1);
  #pragma unroll
  for (int off = 1; off < 64; off <<= 1) mx = fmaxf(mx, __shfl_xor(mx, off));
  float sum = __expf(v0 - mx) + __expf(v1 - mx);
  #pragma unroll
  for (int off = 1; off < 64; off <<= 1) sum += __shfl_xor(sum, off);
  float lse = mx + __logf(sum);
  float2 o = make_float2(v0 - lse, v1 - lse);
  *(float2*)&out[(size_t)node * 128 + lane * 2] = o;
}

// ---------------- host ----------------
extern "C" void kernel_launch(void* const* d_in, const int* in_sizes, int n_in,
                              void* d_out, int out_size, void* d_ws, size_t ws_size,
                              hipStream_t stream) {
  const float* x    = (const float*)d_in[0];
  const void*  ei   = d_in[1];
  const float* W1   = (const float*)d_in[2];
  const float* aS1  = (const float*)d_in[3];
  const float* aD1  = (const float*)d_in[4];
  const float* b1   = (const float*)d_in[5];
  const float* W2   = (const float*)d_in[6];
  const float* aS2  = (const float*)d_in[7];
  const float* aD2  = (const float*)d_in[8];
  const float* b2   = (const float*)d_in[9];
  float* out = (float*)d_out;

  char* ws = (char*)d_ws;
  float* h1   = (float*)ws;            ws += (size_t)NN * 256 * 4;   // reused as h2 after layer-1 agg
  float* hmid = (float*)ws;            ws += (size_t)NN * 256 * 4;
  float* alS  = (float*)ws;            ws += (size_t)NN * 8 * 4;
  float* alD  = (float*)ws;            ws += (size_t)NN * 8 * 4;
  int* counts = (int*)ws;              ws += (size_t)NN * 4;
  int* rs     = (int*)ws;              ws += (size_t)(NN + 1) * 4;
  int* ssrc   = (int*)ws;              ws += (size_t)NE * 4;
  int* flag   = (int*)ws;              ws += 256;

  // ---- CSR build (edge list -> incoming-edge lists per node) ----
  detect_i64_kernel<<<1, 64, 0, stream>>>((const unsigned*)ei, flag);
  hipMemsetAsync(counts, 0, (size_t)NN * 4, stream);
  count_kernel<<<(NE + 255) / 256, 256, 0, stream>>>(ei, flag, counts);
  scan_kernel<<<1, 1024, 0, stream>>>(counts, rs);
  hipMemsetAsync(counts, 0, (size_t)NN * 4, stream);
  scatter_kernel<<<(NE + 255) / 256, 256, 0, stream>>>(ei, flag, rs, counts, ssrc);

  // ---- layer 1 ----
  gemm_f32<64><<<dim3(256 / 64, (NN + 63) / 64), 256, 0, stream>>>(x, W1, h1, NN, 256, 256);
  alpha_kernel<32><<<(NN * 8 + 255) / 256, 256, 0, stream>>>(h1, aS1, aD1, alS, alD);
  agg1_kernel<<<(NN + 3) / 4, 256, 0, stream>>>(h1, alS, alD, rs, ssrc, b1, hmid);

  // ---- layer 2 ----
  gemm_f32<64><<<dim3(128 / 64, (NN + 63) / 64), 256, 0, stream>>>(hmid, W2, h1, NN, 128, 256);
  alpha_kernel<16><<<(NN * 8 + 255) / 256, 256, 0, stream>>>(h1, aS2, aD2, alS, alD);
  agg2_kernel<<<(NN + 3) / 4, 256, 0, stream>>>(h1, alS, alD, rs, ssrc, b2, out);
}

// Round 2
// 541.511 us; speedup vs baseline: 1.0461x; 1.0461x over previous
//
#include <hip/hip_runtime.h>
#include <hip/hip_fp16.h>

#define NN 50000
#define NE 800000

static __device__ __forceinline__ float lrelu(float x) { return x > 0.f ? x : 0.2f * x; }

// ---------------- edge-index dtype detection (int32 vs int64) ----------------
__global__ void detect_i64_kernel(const unsigned* __restrict__ ei, int* __restrict__ flag) {
  if (threadIdx.x == 0 && blockIdx.x == 0) {
    int is64 = 1;
    for (int i = 0; i < 64; ++i)
      if (ei[2 * i + 1] != 0u) { is64 = 0; break; }
    *flag = is64;
  }
}

static __device__ __forceinline__ int edge_at(const void* ei, int is64, long long idx) {
  if (is64) return (int)((const long long*)ei)[idx];
  return ((const int*)ei)[idx];
}

// ---------------- CSR build ----------------
__global__ void count_kernel(const void* __restrict__ ei, const int* __restrict__ flag,
                             int* __restrict__ counts) {
  int e = blockIdx.x * blockDim.x + threadIdx.x;
  if (e >= NE) return;
  int is64 = *flag;
  int d = edge_at(ei, is64, (long long)NE + e);
  atomicAdd(&counts[d], 1);
}

__global__ void scan_kernel(const int* __restrict__ counts, int* __restrict__ rs) {
  __shared__ int wsum[16];
  __shared__ int carry;
  const int tid = threadIdx.x;
  const int lane = tid & 63, wv = tid >> 6;
  if (tid == 0) { carry = 0; rs[0] = 0; }
  __syncthreads();
  for (int base = 0; base < NN; base += 1024) {
    int i = base + tid;
    int v = (i < NN) ? counts[i] : 0;
    #pragma unroll
    for (int off = 1; off < 64; off <<= 1) {
      int t = __shfl_up(v, off);
      if (lane >= off) v += t;
    }
    if (lane == 63) wsum[wv] = v;
    __syncthreads();
    if (tid == 0) {
      int run = 0;
      #pragma unroll
      for (int j = 0; j < 16; ++j) { run += wsum[j]; wsum[j] = run; }
    }
    __syncthreads();
    int add = carry + (wv ? wsum[wv - 1] : 0);
    if (i < NN) rs[i + 1] = add + v;
    __syncthreads();
    if (tid == 0) carry += wsum[15];
    __syncthreads();
  }
}

__global__ void scatter_kernel(const void* __restrict__ ei, const int* __restrict__ flag,
                               const int* __restrict__ rs, int* __restrict__ cursor,
                               int* __restrict__ ssrc) {
  int e = blockIdx.x * blockDim.x + threadIdx.x;
  if (e >= NE) return;
  int is64 = *flag;
  int s = edge_at(ei, is64, e);
  int d = edge_at(ei, is64, (long long)NE + e);
  int p = atomicAdd(&cursor[d], 1);
  ssrc[rs[d] + p] = s;
}

// ---------------- fp32 tiled GEMM, fp16 output: C[M,N] = A[M,K] @ B[K,N] ----
// BM=64, BK=16, 256 threads, each computes 4x4.  N % BN == 0, K % 16 == 0.
template<int BN>
__global__ __launch_bounds__(256) void gemm_f32h(const float* __restrict__ A,
                                                 const float* __restrict__ B,
                                                 __half* __restrict__ C,
                                                 int M, int N, int K) {
  constexpr int BM = 64, BK = 16;
  __shared__ float As[BK][BM + 4];
  __shared__ float Bs[BK][BN];
  const int tid = threadIdx.x;
  const int tx = tid & 15, ty = tid >> 4;
  const int arow = tid >> 2, acol = (tid & 3) << 2;
  const int brow = tid >> 4, bcol = (tid & 15) << 2;
  const int grow = blockIdx.y * BM + arow;
  const int gcolb = blockIdx.x * BN;
  float acc[4][4] = {};
  for (int k0 = 0; k0 < K; k0 += BK) {
    float4 av = make_float4(0.f, 0.f, 0.f, 0.f);
    if (grow < M) av = *(const float4*)&A[(size_t)grow * K + k0 + acol];
    As[acol + 0][arow] = av.x;
    As[acol + 1][arow] = av.y;
    As[acol + 2][arow] = av.z;
    As[acol + 3][arow] = av.w;
    *(float4*)&Bs[brow][bcol] = *(const float4*)&B[(size_t)(k0 + brow) * N + gcolb + bcol];
    __syncthreads();
    #pragma unroll
    for (int kk = 0; kk < BK; ++kk) {
      float a0 = As[kk][ty * 4 + 0], a1 = As[kk][ty * 4 + 1],
            a2 = As[kk][ty * 4 + 2], a3 = As[kk][ty * 4 + 3];
      float b0 = Bs[kk][tx * 4 + 0], b1 = Bs[kk][tx * 4 + 1],
            b2 = Bs[kk][tx * 4 + 2], b3 = Bs[kk][tx * 4 + 3];
      acc[0][0] += a0 * b0; acc[0][1] += a0 * b1; acc[0][2] += a0 * b2; acc[0][3] += a0 * b3;
      acc[1][0] += a1 * b0; acc[1][1] += a1 * b1; acc[1][2] += a1 * b2; acc[1][3] += a1 * b3;
      acc[2][0] += a2 * b0; acc[2][1] += a2 * b1; acc[2][2] += a2 * b2; acc[2][3] += a2 * b3;
      acc[3][0] += a3 * b0; acc[3][1] += a3 * b1; acc[3][2] += a3 * b2; acc[3][3] += a3 * b3;
    }
    __syncthreads();
  }
  #pragma unroll
  for (int i = 0; i < 4; ++i) {
    int r = blockIdx.y * BM + ty * 4 + i;
    if (r < M) {
      union { __half2 h2[2]; float2 f2; } u;
      u.h2[0] = __floats2half2_rn(acc[i][0], acc[i][1]);
      u.h2[1] = __floats2half2_rn(acc[i][2], acc[i][3]);
      *(float2*)&C[(size_t)r * N + gcolb + tx * 4] = u.f2;
    }
  }
}

// ---------------- per-(node,head) attention coefficients (fp16 h) ----------
template<int C>
__global__ void alpha_kernel(const __half* __restrict__ h, const float* __restrict__ aws,
                             const float* __restrict__ awd, float* __restrict__ os,
                             float* __restrict__ od) {
  int i = blockIdx.x * blockDim.x + threadIdx.x;
  if (i >= NN * 8) return;
  int node = i >> 3, head = i & 7;
  const __half2* hp = (const __half2*)(h + (size_t)node * (8 * C) + head * C);
  const float* pws = aws + head * C;
  const float* pwd = awd + head * C;
  float s = 0.f, d = 0.f;
  #pragma unroll
  for (int c = 0; c < C / 2; ++c) {
    float2 v = __half22float2(hp[c]);
    s += v.x * pws[2 * c] + v.y * pws[2 * c + 1];
    d += v.x * pwd[2 * c] + v.y * pwd[2 * c + 1];
  }
  os[i] = s; od[i] = d;
}

// ---------------- layer-1 aggregation (fp16 h): softmax + sum + bias + ELU --
// one wave per node; 256 channels -> 4 per lane; head = lane>>3 in pass 2
__global__ __launch_bounds__(256) void agg1_kernel(const __half* __restrict__ h,
    const float* __restrict__ as, const float* __restrict__ ad,
    const int* __restrict__ rs, const int* __restrict__ ssrc,
    const float* __restrict__ bias, float* __restrict__ out) {
  const int wid = (blockIdx.x * blockDim.x + threadIdx.x) >> 6;
  const int lane = threadIdx.x & 63;
  if (wid >= NN) return;
  const int node = wid;
  const int beg = rs[node], end = rs[node + 1];
  // pass 1: per-head max; head = lane&7, edge-slot = lane>>3 (8 edges parallel)
  const int hA = lane & 7;
  const float advA = ad[node * 8 + hA];
  float m = lrelu(as[node * 8 + hA] + advA);   // self loop
  for (int it = beg + (lane >> 3); it < end; it += 8) {
    int s = ssrc[it];
    m = fmaxf(m, lrelu(as[s * 8 + hA] + advA));
  }
  m = fmaxf(m, __shfl_xor(m, 8));
  m = fmaxf(m, __shfl_xor(m, 16));
  m = fmaxf(m, __shfl_xor(m, 32));
  // pass 2: head = lane>>3, channels 4*lane .. 4*lane+3
  const int hd = lane >> 3;
  const float mh = __shfl(m, hd);
  const float advh = ad[node * 8 + hd];
  float denom;
  float4 acc;
  {
    float p = __expf(lrelu(as[node * 8 + hd] + advh) - mh);   // self loop
    const __half2* hp = (const __half2*)&h[(size_t)node * 256 + lane * 4];
    float2 h01 = __half22float2(hp[0]);
    float2 h23 = __half22float2(hp[1]);
    acc.x = p * h01.x; acc.y = p * h01.y; acc.z = p * h23.x; acc.w = p * h23.y;
    denom = p;
  }
  for (int it = beg; it < end; ++it) {
    int s = ssrc[it];
    float p = __expf(lrelu(as[s * 8 + hd] + advh) - mh);
    const __half2* hp = (const __half2*)&h[(size_t)s * 256 + lane * 4];
    float2 h01 = __half22float2(hp[0]);
    float2 h23 = __half22float2(hp[1]);
    acc.x += p * h01.x; acc.y += p * h01.y; acc.z += p * h23.x; acc.w += p * h23.y;
    denom += p;
  }
  const float inv = 1.f / (denom + 1e-16f);
  const float4 bv = *(const float4*)&bias[lane * 4];
  float4 o;
  o.x = acc.x * inv + bv.x; o.y = acc.y * inv + bv.y;
  o.z = acc.z * inv + bv.z; o.w = acc.w * inv + bv.w;
  o.x = o.x > 0.f ? o.x : __expf(o.x) - 1.f;
  o.y = o.y > 0.f ? o.y : __expf(o.y) - 1.f;
  o.z = o.z > 0.f ? o.z : __expf(o.z) - 1.f;
  o.w = o.w > 0.f ? o.w : __expf(o.w) - 1.f;
  *(float4*)&out[(size_t)node * 256 + lane * 4] = o;
}

// ---------------- layer-2 aggregation (fp16 h) + bias + log_softmax --------
// one wave per node; 128 channels -> 2 per lane; head = lane>>3
__global__ __launch_bounds__(256) void agg2_kernel(const __half* __restrict__ h,
    const float* __restrict__ as, const float* __restrict__ ad,
    const int* __restrict__ rs, const int* __restrict__ ssrc,
    const float* __restrict__ bias, float* __restrict__ out) {
  const int wid = (blockIdx.x * blockDim.x + threadIdx.x) >> 6;
  const int lane = threadIdx.x & 63;
  if (wid >= NN) return;
  const int node = wid;
  const int beg = rs[node], end = rs[node + 1];
  const int hA = lane & 7;
  const float advA = ad[node * 8 + hA];
  float m = lrelu(as[node * 8 + hA] + advA);   // self loop
  for (int it = beg + (lane >> 3); it < end; it += 8) {
    int s = ssrc[it];
    m = fmaxf(m, lrelu(as[s * 8 + hA] + advA));
  }
  m = fmaxf(m, __shfl_xor(m, 8));
  m = fmaxf(m, __shfl_xor(m, 16));
  m = fmaxf(m, __shfl_xor(m, 32));
  const int hd = lane >> 3;
  const float mh = __shfl(m, hd);
  const float advh = ad[node * 8 + hd];
  float denom;
  float2 acc;
  {
    float p = __expf(lrelu(as[node * 8 + hd] + advh) - mh);   // self loop
    float2 hv = __half22float2(((const __half2*)&h[(size_t)node * 128])[lane]);
    acc.x = p * hv.x; acc.y = p * hv.y;
    denom = p;
  }
  for (int it = beg; it < end; ++it) {
    int s = ssrc[it];
    float p = __expf(lrelu(as[s * 8 + hd] + advh) - mh);
    float2 hv = __half22float2(((const __half2*)&h[(size_t)s * 128])[lane]);
    acc.x += p * hv.x; acc.y += p * hv.y;
    denom += p;
  }
  const float inv = 1.f / (denom + 1e-16f);
  float v0 = acc.x * inv + bias[lane * 2 + 0];
  float v1 = acc.y * inv + bias[lane * 2 + 1];
  float mx = fmaxf(v0, v1);
  #pragma unroll
  for (int off = 1; off < 64; off <<= 1) mx = fmaxf(mx, __shfl_xor(mx, off));
  float sum = __expf(v0 - mx) + __expf(v1 - mx);
  #pragma unroll
  for (int off = 1; off < 64; off <<= 1) sum += __shfl_xor(sum, off);
  float lse = mx + __logf(sum);
  float2 o = make_float2(v0 - lse, v1 - lse);
  *(float2*)&out[(size_t)node * 128 + lane * 2] = o;
}

// ---------------- host ----------------
extern "C" void kernel_launch(void* const* d_in, const int* in_sizes, int n_in,
                              void* d_out, int out_size, void* d_ws, size_t ws_size,
                              hipStream_t stream) {
  const float* x    = (const float*)d_in[0];
  const void*  ei   = d_in[1];
  const float* W1   = (const float*)d_in[2];
  const float* aS1  = (const float*)d_in[3];
  const float* aD1  = (const float*)d_in[4];
  const float* b1   = (const float*)d_in[5];
  const float* W2   = (const float*)d_in[6];
  const float* aS2  = (const float*)d_in[7];
  const float* aD2  = (const float*)d_in[8];
  const float* b2   = (const float*)d_in[9];
  float* out = (float*)d_out;

  char* ws = (char*)d_ws;
  __half* hh  = (__half*)ws;           ws += (size_t)NN * 256 * 2;   // fp16 h (layer1), reused for layer2
  float* hmid = (float*)ws;            ws += (size_t)NN * 256 * 4;
  float* alS  = (float*)ws;            ws += (size_t)NN * 8 * 4;
  float* alD  = (float*)ws;            ws += (size_t)NN * 8 * 4;
  int* counts = (int*)ws;              ws += (size_t)NN * 4;
  int* rs     = (int*)ws;              ws += (size_t)(NN + 1) * 4;
  int* ssrc   = (int*)ws;              ws += (size_t)NE * 4;
  int* flag   = (int*)ws;              ws += 256;

  // ---- CSR build (edge list -> incoming-edge lists per node) ----
  detect_i64_kernel<<<1, 64, 0, stream>>>((const unsigned*)ei, flag);
  hipMemsetAsync(counts, 0, (size_t)NN * 4, stream);
  count_kernel<<<(NE + 255) / 256, 256, 0, stream>>>(ei, flag, counts);
  scan_kernel<<<1, 1024, 0, stream>>>(counts, rs);
  hipMemsetAsync(counts, 0, (size_t)NN * 4, stream);
  scatter_kernel<<<(NE + 255) / 256, 256, 0, stream>>>(ei, flag, rs, counts, ssrc);

  // ---- layer 1 ----
  gemm_f32h<64><<<dim3(256 / 64, (NN + 63) / 64), 256, 0, stream>>>(x, W1, hh, NN, 256, 256);
  alpha_kernel<32><<<(NN * 8 + 255) / 256, 256, 0, stream>>>(hh, aS1, aD1, alS, alD);
  agg1_kernel<<<(NN + 3) / 4, 256, 0, stream>>>(hh, alS, alD, rs, ssrc, b1, hmid);

  // ---- layer 2 ----
  gemm_f32h<64><<<dim3(128 / 64, (NN + 63) / 64), 256, 0, stream>>>(hmid, W2, hh, NN, 128, 256);
  alpha_kernel<16><<<(NN * 8 + 255) / 256, 256, 0, stream>>>(hh, aS2, aD2, alS, alD);
  agg2_kernel<<<(NN + 3) / 4, 256, 0, stream>>>(hh, alS, alD, rs, ssrc, b2, out);
}

// Round 3
// 423.792 us; speedup vs baseline: 1.3367x; 1.2778x over previous
//
#include <hip/hip_runtime.h>
#include <hip/hip_fp16.h>

#define NN 50000
#define NE 800000

typedef _Float16 half4v __attribute__((ext_vector_type(4)));
typedef _Float16 half8v __attribute__((ext_vector_type(8)));
typedef float f32x4 __attribute__((ext_vector_type(4)));

static __device__ __forceinline__ float lrelu(float x) { return x > 0.f ? x : 0.2f * x; }

// ---------------- edge-index dtype detection (int32 vs int64) ----------------
__global__ void detect_i64_kernel(const unsigned* __restrict__ ei, int* __restrict__ flag) {
  if (threadIdx.x == 0 && blockIdx.x == 0) {
    int is64 = 1;
    for (int i = 0; i < 64; ++i)
      if (ei[2 * i + 1] != 0u) { is64 = 0; break; }
    *flag = is64;
  }
}

static __device__ __forceinline__ int edge_at(const void* ei, int is64, long long idx) {
  if (is64) return (int)((const long long*)ei)[idx];
  return ((const int*)ei)[idx];
}

// ---------------- CSR build ----------------
__global__ void count_kernel(const void* __restrict__ ei, const int* __restrict__ flag,
                             int* __restrict__ counts) {
  int e = blockIdx.x * blockDim.x + threadIdx.x;
  if (e >= NE) return;
  int is64 = *flag;
  int d = edge_at(ei, is64, (long long)NE + e);
  atomicAdd(&counts[d], 1);
}

__global__ void scan_kernel(const int* __restrict__ counts, int* __restrict__ rs) {
  __shared__ int wsum[16];
  __shared__ int carry;
  const int tid = threadIdx.x;
  const int lane = tid & 63, wv = tid >> 6;
  if (tid == 0) { carry = 0; rs[0] = 0; }
  __syncthreads();
  for (int base = 0; base < NN; base += 1024) {
    int i = base + tid;
    int v = (i < NN) ? counts[i] : 0;
    #pragma unroll
    for (int off = 1; off < 64; off <<= 1) {
      int t = __shfl_up(v, off);
      if (lane >= off) v += t;
    }
    if (lane == 63) wsum[wv] = v;
    __syncthreads();
    if (tid == 0) {
      int run = 0;
      #pragma unroll
      for (int j = 0; j < 16; ++j) { run += wsum[j]; wsum[j] = run; }
    }
    __syncthreads();
    int add = carry + (wv ? wsum[wv - 1] : 0);
    if (i < NN) rs[i + 1] = add + v;
    __syncthreads();
    if (tid == 0) carry += wsum[15];
    __syncthreads();
  }
}

__global__ void scatter_kernel(const void* __restrict__ ei, const int* __restrict__ flag,
                               const int* __restrict__ rs, int* __restrict__ cursor,
                               int* __restrict__ ssrc) {
  int e = blockIdx.x * blockDim.x + threadIdx.x;
  if (e >= NE) return;
  int is64 = *flag;
  int s = edge_at(ei, is64, e);
  int d = edge_at(ei, is64, (long long)NE + e);
  int p = atomicAdd(&cursor[d], 1);
  ssrc[rs[d] + p] = s;
}

// ---------------- weight transpose + fp16 convert: Wt[n][k] = W[k][n], K=256 --
__global__ void convert_wt_kernel(const float* __restrict__ W, _Float16* __restrict__ Wt,
                                  int N, int total) {
  int i = blockIdx.x * blockDim.x + threadIdx.x;
  if (i >= total) return;
  int n = i >> 8, k = i & 255;
  Wt[i] = (_Float16)W[(size_t)k * N + n];
}

// ---------------- MFMA fp16 GEMM: C[M,BN] = A[M,256] @ Wt^T ------------------
// BM=64 rows/block, full-N per block (A-panel read exactly once).
// 4 waves; wave w owns cols [w*16*NCF, ...). 16x16x32 f16 MFMA, fp32 acc.
// A layout in LDS: [64][256+8] fp16 (pad -> ~2-way bank conflicts, free).
// A-frag: lane l -> row (l&15), k = 8*(l>>4)+j (j=0..7)
// B-frag: lane l -> col (l&15), k = 8*(l>>4)+j   (from Wt[n][k], contiguous 16B)
// C/D:    lane l -> col (l&15), row = 4*(l>>4)+j
template<int BN, int NCF, bool A_HALF>
__global__ __launch_bounds__(256) void gemm_mfma(const void* __restrict__ Araw,
                                                 const _Float16* __restrict__ Wt,
                                                 __half* __restrict__ C, int M) {
  __shared__ _Float16 As[64][256 + 8];
  const int tid = threadIdx.x;
  const int bm0 = blockIdx.x * 64;
  // ---- stage A tile (convert fp32->fp16 if needed) ----
  if (A_HALF) {
    const _Float16* A = (const _Float16*)Araw;
    for (int idx = tid; idx < 64 * 32; idx += 256) {
      int r = idx >> 5, c8 = (idx & 31) << 3;
      int gr = bm0 + r;
      half8v v = {};
      if (gr < M) v = *(const half8v*)&A[(size_t)gr * 256 + c8];
      *(half8v*)&As[r][c8] = v;
    }
  } else {
    const float* A = (const float*)Araw;
    for (int idx = tid; idx < 64 * 64; idx += 256) {
      int r = idx >> 6, c4 = (idx & 63) << 2;
      int gr = bm0 + r;
      float4 v = make_float4(0.f, 0.f, 0.f, 0.f);
      if (gr < M) v = *(const float4*)&A[(size_t)gr * 256 + c4];
      half4v h = { (_Float16)v.x, (_Float16)v.y, (_Float16)v.z, (_Float16)v.w };
      *(half4v*)&As[r][c4] = h;
    }
  }
  __syncthreads();
  const int lane = tid & 63, wv = tid >> 6;
  const int ncol0 = wv * (16 * NCF);
  const int lrow = lane & 15, lk8 = (lane >> 4) << 3;
  f32x4 acc[4][NCF];
  #pragma unroll
  for (int rf = 0; rf < 4; ++rf)
    #pragma unroll
    for (int cf = 0; cf < NCF; ++cf) acc[rf][cf] = (f32x4){0.f, 0.f, 0.f, 0.f};
  #pragma unroll
  for (int k0 = 0; k0 < 256; k0 += 32) {
    const int ks = k0 + lk8;
    half8v af[4];
    #pragma unroll
    for (int rf = 0; rf < 4; ++rf)
      af[rf] = *(const half8v*)&As[16 * rf + lrow][ks];
    #pragma unroll
    for (int cf = 0; cf < NCF; ++cf) {
      half8v bf = *(const half8v*)&Wt[(size_t)(ncol0 + 16 * cf + lrow) * 256 + ks];
      #pragma unroll
      for (int rf = 0; rf < 4; ++rf)
        acc[rf][cf] = __builtin_amdgcn_mfma_f32_16x16x32_f16(af[rf], bf, acc[rf][cf], 0, 0, 0);
    }
  }
  // ---- store C (fp16) ----
  #pragma unroll
  for (int rf = 0; rf < 4; ++rf) {
    #pragma unroll
    for (int j = 0; j < 4; ++j) {
      int row = bm0 + 16 * rf + 4 * (lane >> 4) + j;
      if (row < M) {
        #pragma unroll
        for (int cf = 0; cf < NCF; ++cf) {
          int col = ncol0 + 16 * cf + lrow;
          C[(size_t)row * BN + col] = __float2half(acc[rf][cf][j]);
        }
      }
    }
  }
}

// ---------------- per-(node,head) attention coefficients (fp16 h) ----------
template<int C>
__global__ void alpha_kernel(const __half* __restrict__ h, const float* __restrict__ aws,
                             const float* __restrict__ awd, float* __restrict__ os,
                             float* __restrict__ od) {
  int i = blockIdx.x * blockDim.x + threadIdx.x;
  if (i >= NN * 8) return;
  int node = i >> 3, head = i & 7;
  const __half2* hp = (const __half2*)(h + (size_t)node * (8 * C) + head * C);
  const float* pws = aws + head * C;
  const float* pwd = awd + head * C;
  float s = 0.f, d = 0.f;
  #pragma unroll
  for (int c = 0; c < C / 2; ++c) {
    float2 v = __half22float2(hp[c]);
    s += v.x * pws[2 * c] + v.y * pws[2 * c + 1];
    d += v.x * pwd[2 * c] + v.y * pwd[2 * c + 1];
  }
  os[i] = s; od[i] = d;
}

// ---------------- layer-1 aggregation (fp16 h): softmax + sum + bias + ELU --
// one wave per node; out = fp16 (feeds MFMA gemm2)
__global__ __launch_bounds__(256) void agg1_kernel(const __half* __restrict__ h,
    const float* __restrict__ as, const float* __restrict__ ad,
    const int* __restrict__ rs, const int* __restrict__ ssrc,
    const float* __restrict__ bias, __half* __restrict__ out) {
  const int wid = (blockIdx.x * blockDim.x + threadIdx.x) >> 6;
  const int lane = threadIdx.x & 63;
  if (wid >= NN) return;
  const int node = wid;
  const int beg = rs[node], end = rs[node + 1];
  const int hA = lane & 7;
  const float advA = ad[node * 8 + hA];
  float m = lrelu(as[node * 8 + hA] + advA);   // self loop
  for (int it = beg + (lane >> 3); it < end; it += 8) {
    int s = ssrc[it];
    m = fmaxf(m, lrelu(as[s * 8 + hA] + advA));
  }
  m = fmaxf(m, __shfl_xor(m, 8));
  m = fmaxf(m, __shfl_xor(m, 16));
  m = fmaxf(m, __shfl_xor(m, 32));
  const int hd = lane >> 3;
  const float mh = __shfl(m, hd);
  const float advh = ad[node * 8 + hd];
  float denom;
  float4 acc;
  {
    float p = __expf(lrelu(as[node * 8 + hd] + advh) - mh);   // self loop
    const __half2* hp = (const __half2*)&h[(size_t)node * 256 + lane * 4];
    float2 h01 = __half22float2(hp[0]);
    float2 h23 = __half22float2(hp[1]);
    acc.x = p * h01.x; acc.y = p * h01.y; acc.z = p * h23.x; acc.w = p * h23.y;
    denom = p;
  }
  for (int it = beg; it < end; ++it) {
    int s = ssrc[it];
    float p = __expf(lrelu(as[s * 8 + hd] + advh) - mh);
    const __half2* hp = (const __half2*)&h[(size_t)s * 256 + lane * 4];
    float2 h01 = __half22float2(hp[0]);
    float2 h23 = __half22float2(hp[1]);
    acc.x += p * h01.x; acc.y += p * h01.y; acc.z += p * h23.x; acc.w += p * h23.y;
    denom += p;
  }
  const float inv = 1.f / (denom + 1e-16f);
  const float4 bv = *(const float4*)&bias[lane * 4];
  float4 o;
  o.x = acc.x * inv + bv.x; o.y = acc.y * inv + bv.y;
  o.z = acc.z * inv + bv.z; o.w = acc.w * inv + bv.w;
  o.x = o.x > 0.f ? o.x : __expf(o.x) - 1.f;
  o.y = o.y > 0.f ? o.y : __expf(o.y) - 1.f;
  o.z = o.z > 0.f ? o.z : __expf(o.z) - 1.f;
  o.w = o.w > 0.f ? o.w : __expf(o.w) - 1.f;
  union { __half2 h2[2]; float2 f2; } u;
  u.h2[0] = __floats2half2_rn(o.x, o.y);
  u.h2[1] = __floats2half2_rn(o.z, o.w);
  *(float2*)&out[(size_t)node * 256 + lane * 4] = u.f2;
}

// ---------------- layer-2 aggregation (fp16 h) + bias + log_softmax --------
__global__ __launch_bounds__(256) void agg2_kernel(const __half* __restrict__ h,
    const float* __restrict__ as, const float* __restrict__ ad,
    const int* __restrict__ rs, const int* __restrict__ ssrc,
    const float* __restrict__ bias, float* __restrict__ out) {
  const int wid = (blockIdx.x * blockDim.x + threadIdx.x) >> 6;
  const int lane = threadIdx.x & 63;
  if (wid >= NN) return;
  const int node = wid;
  const int beg = rs[node], end = rs[node + 1];
  const int hA = lane & 7;
  const float advA = ad[node * 8 + hA];
  float m = lrelu(as[node * 8 + hA] + advA);   // self loop
  for (int it = beg + (lane >> 3); it < end; it += 8) {
    int s = ssrc[it];
    m = fmaxf(m, lrelu(as[s * 8 + hA] + advA));
  }
  m = fmaxf(m, __shfl_xor(m, 8));
  m = fmaxf(m, __shfl_xor(m, 16));
  m = fmaxf(m, __shfl_xor(m, 32));
  const int hd = lane >> 3;
  const float mh = __shfl(m, hd);
  const float advh = ad[node * 8 + hd];
  float denom;
  float2 acc;
  {
    float p = __expf(lrelu(as[node * 8 + hd] + advh) - mh);   // self loop
    float2 hv = __half22float2(((const __half2*)&h[(size_t)node * 128])[lane]);
    acc.x = p * hv.x; acc.y = p * hv.y;
    denom = p;
  }
  for (int it = beg; it < end; ++it) {
    int s = ssrc[it];
    float p = __expf(lrelu(as[s * 8 + hd] + advh) - mh);
    float2 hv = __half22float2(((const __half2*)&h[(size_t)s * 128])[lane]);
    acc.x += p * hv.x; acc.y += p * hv.y;
    denom += p;
  }
  const float inv = 1.f / (denom + 1e-16f);
  float v0 = acc.x * inv + bias[lane * 2 + 0];
  float v1 = acc.y * inv + bias[lane * 2 + 1];
  float mx = fmaxf(v0, v1);
  #pragma unroll
  for (int off = 1; off < 64; off <<= 1) mx = fmaxf(mx, __shfl_xor(mx, off));
  float sum = __expf(v0 - mx) + __expf(v1 - mx);
  #pragma unroll
  for (int off = 1; off < 64; off <<= 1) sum += __shfl_xor(sum, off);
  float lse = mx + __logf(sum);
  float2 o = make_float2(v0 - lse, v1 - lse);
  *(float2*)&out[(size_t)node * 128 + lane * 2] = o;
}

// ---------------- host ----------------
extern "C" void kernel_launch(void* const* d_in, const int* in_sizes, int n_in,
                              void* d_out, int out_size, void* d_ws, size_t ws_size,
                              hipStream_t stream) {
  const float* x    = (const float*)d_in[0];
  const void*  ei   = d_in[1];
  const float* W1   = (const float*)d_in[2];
  const float* aS1  = (const float*)d_in[3];
  const float* aD1  = (const float*)d_in[4];
  const float* b1   = (const float*)d_in[5];
  const float* W2   = (const float*)d_in[6];
  const float* aS2  = (const float*)d_in[7];
  const float* aD2  = (const float*)d_in[8];
  const float* b2   = (const float*)d_in[9];
  float* out = (float*)d_out;

  char* ws = (char*)d_ws;
  __half* hh   = (__half*)ws;          ws += (size_t)NN * 256 * 2;  // h (layer1) / h2 (layer2)
  __half* hmid = (__half*)ws;          ws += (size_t)NN * 256 * 2;  // ELU(agg1) fp16
  _Float16* W1t = (_Float16*)ws;       ws += (size_t)256 * 256 * 2; // [N=256][K=256]
  _Float16* W2t = (_Float16*)ws;       ws += (size_t)128 * 256 * 2; // [N=128][K=256]
  float* alS  = (float*)ws;            ws += (size_t)NN * 8 * 4;
  float* alD  = (float*)ws;            ws += (size_t)NN * 8 * 4;
  int* counts = (int*)ws;              ws += (size_t)NN * 4;
  int* rs     = (int*)ws;              ws += (size_t)(NN + 1) * 4;
  int* ssrc   = (int*)ws;              ws += (size_t)NE * 4;
  int* flag   = (int*)ws;              ws += 256;

  // ---- CSR build ----
  detect_i64_kernel<<<1, 64, 0, stream>>>((const unsigned*)ei, flag);
  hipMemsetAsync(counts, 0, (size_t)NN * 4, stream);
  count_kernel<<<(NE + 255) / 256, 256, 0, stream>>>(ei, flag, counts);
  scan_kernel<<<1, 1024, 0, stream>>>(counts, rs);
  hipMemsetAsync(counts, 0, (size_t)NN * 4, stream);
  scatter_kernel<<<(NE + 255) / 256, 256, 0, stream>>>(ei, flag, rs, counts, ssrc);

  // ---- weight prep ----
  convert_wt_kernel<<<(256 * 256 + 255) / 256, 256, 0, stream>>>(W1, W1t, 256, 256 * 256);
  convert_wt_kernel<<<(128 * 256 + 255) / 256, 256, 0, stream>>>(W2, W2t, 128, 128 * 256);

  const int ngrid = (NN + 63) / 64;  // 782
  // ---- layer 1 ----
  gemm_mfma<256, 4, false><<<ngrid, 256, 0, stream>>>(x, W1t, hh, NN);
  alpha_kernel<32><<<(NN * 8 + 255) / 256, 256, 0, stream>>>(hh, aS1, aD1, alS, alD);
  agg1_kernel<<<(NN + 3) / 4, 256, 0, stream>>>(hh, alS, alD, rs, ssrc, b1, hmid);

  // ---- layer 2 ----
  gemm_mfma<128, 2, true><<<ngrid, 256, 0, stream>>>(hmid, W2t, hh, NN);
  alpha_kernel<16><<<(NN * 8 + 255) / 256, 256, 0, stream>>>(hh, aS2, aD2, alS, alD);
  agg2_kernel<<<(NN + 3) / 4, 256, 0, stream>>>(hh, alS, alD, rs, ssrc, b2, out);
}

// Round 4
// 337.462 us; speedup vs baseline: 1.6787x; 1.2558x over previous
//
#include <hip/hip_runtime.h>
#include <hip/hip_fp16.h>

#define NN 50000
#define NE 800000

typedef _Float16 half4v __attribute__((ext_vector_type(4)));
typedef _Float16 half8v __attribute__((ext_vector_type(8)));
typedef float f32x4 __attribute__((ext_vector_type(4)));

static __device__ __forceinline__ float lrelu(float x) { return x > 0.f ? x : 0.2f * x; }

// ---------------- edge-index dtype detection (int32 vs int64) ----------------
__global__ void detect_i64_kernel(const unsigned* __restrict__ ei, int* __restrict__ flag) {
  if (threadIdx.x == 0 && blockIdx.x == 0) {
    int is64 = 1;
    for (int i = 0; i < 64; ++i)
      if (ei[2 * i + 1] != 0u) { is64 = 0; break; }
    *flag = is64;
  }
}

static __device__ __forceinline__ int edge_at(const void* ei, int is64, long long idx) {
  if (is64) return (int)((const long long*)ei)[idx];
  return ((const int*)ei)[idx];
}

// ---------------- CSR build ----------------
__global__ void count_kernel(const void* __restrict__ ei, const int* __restrict__ flag,
                             int* __restrict__ counts) {
  int e = blockIdx.x * blockDim.x + threadIdx.x;
  if (e >= NE) return;
  int is64 = *flag;
  int d = edge_at(ei, is64, (long long)NE + e);
  atomicAdd(&counts[d], 1);
}

__global__ void scan_kernel(const int* __restrict__ counts, int* __restrict__ rs) {
  __shared__ int wsum[16];
  __shared__ int carry;
  const int tid = threadIdx.x;
  const int lane = tid & 63, wv = tid >> 6;
  if (tid == 0) { carry = 0; rs[0] = 0; }
  __syncthreads();
  for (int base = 0; base < NN; base += 1024) {
    int i = base + tid;
    int v = (i < NN) ? counts[i] : 0;
    #pragma unroll
    for (int off = 1; off < 64; off <<= 1) {
      int t = __shfl_up(v, off);
      if (lane >= off) v += t;
    }
    if (lane == 63) wsum[wv] = v;
    __syncthreads();
    if (tid == 0) {
      int run = 0;
      #pragma unroll
      for (int j = 0; j < 16; ++j) { run += wsum[j]; wsum[j] = run; }
    }
    __syncthreads();
    int add = carry + (wv ? wsum[wv - 1] : 0);
    if (i < NN) rs[i + 1] = add + v;
    __syncthreads();
    if (tid == 0) carry += wsum[15];
    __syncthreads();
  }
}

__global__ void scatter_kernel(const void* __restrict__ ei, const int* __restrict__ flag,
                               const int* __restrict__ rs, int* __restrict__ cursor,
                               int* __restrict__ ssrc) {
  int e = blockIdx.x * blockDim.x + threadIdx.x;
  if (e >= NE) return;
  int is64 = *flag;
  int s = edge_at(ei, is64, e);
  int d = edge_at(ei, is64, (long long)NE + e);
  int p = atomicAdd(&cursor[d], 1);
  ssrc[rs[d] + p] = s;
}

// ---------------- weight transpose + fp16 convert: Wt[n][k] = W[k][n], K=256 --
__global__ void convert_wt_kernel(const float* __restrict__ W, _Float16* __restrict__ Wt,
                                  int N, int total) {
  int i = blockIdx.x * blockDim.x + threadIdx.x;
  if (i >= total) return;
  int n = i >> 8, k = i & 255;
  Wt[i] = (_Float16)W[(size_t)k * N + n];
}

// ---------------- MFMA fp16 GEMM: C[M,BN] = A[M,256] @ Wt^T ------------------
template<int BN, int NCF, bool A_HALF>
__global__ __launch_bounds__(256) void gemm_mfma(const void* __restrict__ Araw,
                                                 const _Float16* __restrict__ Wt,
                                                 __half* __restrict__ C, int M) {
  __shared__ _Float16 As[64][256 + 8];
  const int tid = threadIdx.x;
  const int bm0 = blockIdx.x * 64;
  if (A_HALF) {
    const _Float16* A = (const _Float16*)Araw;
    for (int idx = tid; idx < 64 * 32; idx += 256) {
      int r = idx >> 5, c8 = (idx & 31) << 3;
      int gr = bm0 + r;
      half8v v = {};
      if (gr < M) v = *(const half8v*)&A[(size_t)gr * 256 + c8];
      *(half8v*)&As[r][c8] = v;
    }
  } else {
    const float* A = (const float*)Araw;
    for (int idx = tid; idx < 64 * 64; idx += 256) {
      int r = idx >> 6, c4 = (idx & 63) << 2;
      int gr = bm0 + r;
      float4 v = make_float4(0.f, 0.f, 0.f, 0.f);
      if (gr < M) v = *(const float4*)&A[(size_t)gr * 256 + c4];
      half4v h = { (_Float16)v.x, (_Float16)v.y, (_Float16)v.z, (_Float16)v.w };
      *(half4v*)&As[r][c4] = h;
    }
  }
  __syncthreads();
  const int lane = tid & 63, wv = tid >> 6;
  const int ncol0 = wv * (16 * NCF);
  const int lrow = lane & 15, lk8 = (lane >> 4) << 3;
  f32x4 acc[4][NCF];
  #pragma unroll
  for (int rf = 0; rf < 4; ++rf)
    #pragma unroll
    for (int cf = 0; cf < NCF; ++cf) acc[rf][cf] = (f32x4){0.f, 0.f, 0.f, 0.f};
  #pragma unroll
  for (int k0 = 0; k0 < 256; k0 += 32) {
    const int ks = k0 + lk8;
    half8v af[4];
    #pragma unroll
    for (int rf = 0; rf < 4; ++rf)
      af[rf] = *(const half8v*)&As[16 * rf + lrow][ks];
    #pragma unroll
    for (int cf = 0; cf < NCF; ++cf) {
      half8v bf = *(const half8v*)&Wt[(size_t)(ncol0 + 16 * cf + lrow) * 256 + ks];
      #pragma unroll
      for (int rf = 0; rf < 4; ++rf)
        acc[rf][cf] = __builtin_amdgcn_mfma_f32_16x16x32_f16(af[rf], bf, acc[rf][cf], 0, 0, 0);
    }
  }
  #pragma unroll
  for (int rf = 0; rf < 4; ++rf) {
    #pragma unroll
    for (int j = 0; j < 4; ++j) {
      int row = bm0 + 16 * rf + 4 * (lane >> 4) + j;
      if (row < M) {
        #pragma unroll
        for (int cf = 0; cf < NCF; ++cf) {
          int col = ncol0 + 16 * cf + lrow;
          C[(size_t)row * BN + col] = __float2half(acc[rf][cf][j]);
        }
      }
    }
  }
}

// ---------------- per-(node,head) attention coefficients (fp16 h) ----------
template<int C>
__global__ void alpha_kernel(const __half* __restrict__ h, const float* __restrict__ aws,
                             const float* __restrict__ awd, float* __restrict__ os,
                             float* __restrict__ od) {
  int i = blockIdx.x * blockDim.x + threadIdx.x;
  if (i >= NN * 8) return;
  int node = i >> 3, head = i & 7;
  const __half2* hp = (const __half2*)(h + (size_t)node * (8 * C) + head * C);
  const float* pws = aws + head * C;
  const float* pwd = awd + head * C;
  float s = 0.f, d = 0.f;
  #pragma unroll
  for (int c = 0; c < C / 2; ++c) {
    float2 v = __half22float2(hp[c]);
    s += v.x * pws[2 * c] + v.y * pws[2 * c + 1];
    d += v.x * pwd[2 * c] + v.y * pwd[2 * c + 1];
  }
  os[i] = s; od[i] = d;
}

// ---------------- layer-1 aggregation (fp16 h): softmax + sum + bias + ELU --
// one wave per node; 4-deep pipelined edge loop for MLP
__global__ __launch_bounds__(256) void agg1_kernel(const __half* __restrict__ h,
    const float* __restrict__ as, const float* __restrict__ ad,
    const int* __restrict__ rs, const int* __restrict__ ssrc,
    const float* __restrict__ bias, __half* __restrict__ out) {
  const int wid = (blockIdx.x * blockDim.x + threadIdx.x) >> 6;
  const int lane = threadIdx.x & 63;
  if (wid >= NN) return;
  const int node = wid;
  const int beg = rs[node], end = rs[node + 1];
  // ---- pass 1: per-head max (8 edges x 8 heads per iter, unroll 2) ----
  const int hA = lane & 7;
  const float advA = ad[node * 8 + hA];
  float m = lrelu(as[node * 8 + hA] + advA);   // self loop
  {
    int it = beg + (lane >> 3);
    for (; it + 8 < end; it += 16) {
      int s0 = ssrc[it], s1 = ssrc[it + 8];
      float e0 = as[s0 * 8 + hA], e1 = as[s1 * 8 + hA];
      m = fmaxf(m, lrelu(e0 + advA));
      m = fmaxf(m, lrelu(e1 + advA));
    }
    if (it < end) {
      int s0 = ssrc[it];
      m = fmaxf(m, lrelu(as[s0 * 8 + hA] + advA));
    }
  }
  m = fmaxf(m, __shfl_xor(m, 8));
  m = fmaxf(m, __shfl_xor(m, 16));
  m = fmaxf(m, __shfl_xor(m, 32));
  // ---- pass 2: weighted sum, 4-deep pipeline ----
  const int hd = lane >> 3;
  const float mh = __shfl(m, hd);
  const float advh = ad[node * 8 + hd];
  float denom;
  float4 acc;
  {
    float p = __expf(lrelu(as[node * 8 + hd] + advh) - mh);   // self loop
    union { float2 f; __half2 q[2]; } u;
    u.f = *(const float2*)&h[(size_t)node * 256 + lane * 4];
    float2 h01 = __half22float2(u.q[0]);
    float2 h23 = __half22float2(u.q[1]);
    acc.x = p * h01.x; acc.y = p * h01.y; acc.z = p * h23.x; acc.w = p * h23.y;
    denom = p;
  }
  int it = beg;
  for (; it + 4 <= end; it += 4) {
    int s0 = ssrc[it], s1 = ssrc[it + 1], s2 = ssrc[it + 2], s3 = ssrc[it + 3];
    float b0 = as[s0 * 8 + hd], b1 = as[s1 * 8 + hd],
          b2 = as[s2 * 8 + hd], b3 = as[s3 * 8 + hd];
    union { float2 f; __half2 q[2]; } u0, u1, u2, u3;
    u0.f = *(const float2*)&h[(size_t)s0 * 256 + lane * 4];
    u1.f = *(const float2*)&h[(size_t)s1 * 256 + lane * 4];
    u2.f = *(const float2*)&h[(size_t)s2 * 256 + lane * 4];
    u3.f = *(const float2*)&h[(size_t)s3 * 256 + lane * 4];
    float p0 = __expf(lrelu(b0 + advh) - mh);
    float p1 = __expf(lrelu(b1 + advh) - mh);
    float p2 = __expf(lrelu(b2 + advh) - mh);
    float p3 = __expf(lrelu(b3 + advh) - mh);
    denom += p0 + p1 + p2 + p3;
    float2 a01, a23;
    a01 = __half22float2(u0.q[0]); a23 = __half22float2(u0.q[1]);
    acc.x += p0 * a01.x; acc.y += p0 * a01.y; acc.z += p0 * a23.x; acc.w += p0 * a23.y;
    a01 = __half22float2(u1.q[0]); a23 = __half22float2(u1.q[1]);
    acc.x += p1 * a01.x; acc.y += p1 * a01.y; acc.z += p1 * a23.x; acc.w += p1 * a23.y;
    a01 = __half22float2(u2.q[0]); a23 = __half22float2(u2.q[1]);
    acc.x += p2 * a01.x; acc.y += p2 * a01.y; acc.z += p2 * a23.x; acc.w += p2 * a23.y;
    a01 = __half22float2(u3.q[0]); a23 = __half22float2(u3.q[1]);
    acc.x += p3 * a01.x; acc.y += p3 * a01.y; acc.z += p3 * a23.x; acc.w += p3 * a23.y;
  }
  for (; it < end; ++it) {
    int s = ssrc[it];
    float p = __expf(lrelu(as[s * 8 + hd] + advh) - mh);
    union { float2 f; __half2 q[2]; } u;
    u.f = *(const float2*)&h[(size_t)s * 256 + lane * 4];
    float2 h01 = __half22float2(u.q[0]);
    float2 h23 = __half22float2(u.q[1]);
    acc.x += p * h01.x; acc.y += p * h01.y; acc.z += p * h23.x; acc.w += p * h23.y;
    denom += p;
  }
  const float inv = 1.f / (denom + 1e-16f);
  const float4 bv = *(const float4*)&bias[lane * 4];
  float4 o;
  o.x = acc.x * inv + bv.x; o.y = acc.y * inv + bv.y;
  o.z = acc.z * inv + bv.z; o.w = acc.w * inv + bv.w;
  o.x = o.x > 0.f ? o.x : __expf(o.x) - 1.f;
  o.y = o.y > 0.f ? o.y : __expf(o.y) - 1.f;
  o.z = o.z > 0.f ? o.z : __expf(o.z) - 1.f;
  o.w = o.w > 0.f ? o.w : __expf(o.w) - 1.f;
  union { __half2 h2[2]; float2 f2; } u;
  u.h2[0] = __floats2half2_rn(o.x, o.y);
  u.h2[1] = __floats2half2_rn(o.z, o.w);
  *(float2*)&out[(size_t)node * 256 + lane * 4] = u.f2;
}

// ---------------- layer-2 aggregation (fp16 h) + bias + log_softmax --------
__global__ __launch_bounds__(256) void agg2_kernel(const __half* __restrict__ h,
    const float* __restrict__ as, const float* __restrict__ ad,
    const int* __restrict__ rs, const int* __restrict__ ssrc,
    const float* __restrict__ bias, float* __restrict__ out) {
  const int wid = (blockIdx.x * blockDim.x + threadIdx.x) >> 6;
  const int lane = threadIdx.x & 63;
  if (wid >= NN) return;
  const int node = wid;
  const int beg = rs[node], end = rs[node + 1];
  const int hA = lane & 7;
  const float advA = ad[node * 8 + hA];
  float m = lrelu(as[node * 8 + hA] + advA);   // self loop
  {
    int it = beg + (lane >> 3);
    for (; it + 8 < end; it += 16) {
      int s0 = ssrc[it], s1 = ssrc[it + 8];
      float e0 = as[s0 * 8 + hA], e1 = as[s1 * 8 + hA];
      m = fmaxf(m, lrelu(e0 + advA));
      m = fmaxf(m, lrelu(e1 + advA));
    }
    if (it < end) {
      int s0 = ssrc[it];
      m = fmaxf(m, lrelu(as[s0 * 8 + hA] + advA));
    }
  }
  m = fmaxf(m, __shfl_xor(m, 8));
  m = fmaxf(m, __shfl_xor(m, 16));
  m = fmaxf(m, __shfl_xor(m, 32));
  const int hd = lane >> 3;
  const float mh = __shfl(m, hd);
  const float advh = ad[node * 8 + hd];
  float denom;
  float2 acc;
  {
    float p = __expf(lrelu(as[node * 8 + hd] + advh) - mh);   // self loop
    float2 hv = __half22float2(((const __half2*)&h[(size_t)node * 128])[lane]);
    acc.x = p * hv.x; acc.y = p * hv.y;
    denom = p;
  }
  int it = beg;
  for (; it + 4 <= end; it += 4) {
    int s0 = ssrc[it], s1 = ssrc[it + 1], s2 = ssrc[it + 2], s3 = ssrc[it + 3];
    float b0 = as[s0 * 8 + hd], b1 = as[s1 * 8 + hd],
          b2 = as[s2 * 8 + hd], b3 = as[s3 * 8 + hd];
    __half2 q0 = ((const __half2*)&h[(size_t)s0 * 128])[lane];
    __half2 q1 = ((const __half2*)&h[(size_t)s1 * 128])[lane];
    __half2 q2 = ((const __half2*)&h[(size_t)s2 * 128])[lane];
    __half2 q3 = ((const __half2*)&h[(size_t)s3 * 128])[lane];
    float p0 = __expf(lrelu(b0 + advh) - mh);
    float p1 = __expf(lrelu(b1 + advh) - mh);
    float p2 = __expf(lrelu(b2 + advh) - mh);
    float p3 = __expf(lrelu(b3 + advh) - mh);
    denom += p0 + p1 + p2 + p3;
    float2 v;
    v = __half22float2(q0); acc.x += p0 * v.x; acc.y += p0 * v.y;
    v = __half22float2(q1); acc.x += p1 * v.x; acc.y += p1 * v.y;
    v = __half22float2(q2); acc.x += p2 * v.x; acc.y += p2 * v.y;
    v = __half22float2(q3); acc.x += p3 * v.x; acc.y += p3 * v.y;
  }
  for (; it < end; ++it) {
    int s = ssrc[it];
    float p = __expf(lrelu(as[s * 8 + hd] + advh) - mh);
    float2 hv = __half22float2(((const __half2*)&h[(size_t)s * 128])[lane]);
    acc.x += p * hv.x; acc.y += p * hv.y;
    denom += p;
  }
  const float inv = 1.f / (denom + 1e-16f);
  float v0 = acc.x * inv + bias[lane * 2 + 0];
  float v1 = acc.y * inv + bias[lane * 2 + 1];
  float mx = fmaxf(v0, v1);
  #pragma unroll
  for (int off = 1; off < 64; off <<= 1) mx = fmaxf(mx, __shfl_xor(mx, off));
  float sum = __expf(v0 - mx) + __expf(v1 - mx);
  #pragma unroll
  for (int off = 1; off < 64; off <<= 1) sum += __shfl_xor(sum, off);
  float lse = mx + __logf(sum);
  float2 o = make_float2(v0 - lse, v1 - lse);
  __builtin_nontemporal_store(o.x, &out[(size_t)node * 128 + lane * 2]);
  __builtin_nontemporal_store(o.y, &out[(size_t)node * 128 + lane * 2 + 1]);
}

// ---------------- host ----------------
extern "C" void kernel_launch(void* const* d_in, const int* in_sizes, int n_in,
                              void* d_out, int out_size, void* d_ws, size_t ws_size,
                              hipStream_t stream) {
  const float* x    = (const float*)d_in[0];
  const void*  ei   = d_in[1];
  const float* W1   = (const float*)d_in[2];
  const float* aS1  = (const float*)d_in[3];
  const float* aD1  = (const float*)d_in[4];
  const float* b1   = (const float*)d_in[5];
  const float* W2   = (const float*)d_in[6];
  const float* aS2  = (const float*)d_in[7];
  const float* aD2  = (const float*)d_in[8];
  const float* b2   = (const float*)d_in[9];
  float* out = (float*)d_out;

  char* ws = (char*)d_ws;
  __half* hh   = (__half*)ws;          ws += (size_t)NN * 256 * 2;  // h (layer1) / h2 (layer2)
  __half* hmid = (__half*)ws;          ws += (size_t)NN * 256 * 2;  // ELU(agg1) fp16
  _Float16* W1t = (_Float16*)ws;       ws += (size_t)256 * 256 * 2; // [N=256][K=256]
  _Float16* W2t = (_Float16*)ws;       ws += (size_t)128 * 256 * 2; // [N=128][K=256]
  float* alS  = (float*)ws;            ws += (size_t)NN * 8 * 4;
  float* alD  = (float*)ws;            ws += (size_t)NN * 8 * 4;
  int* counts = (int*)ws;              ws += (size_t)NN * 4;
  int* rs     = (int*)ws;              ws += (size_t)(NN + 1) * 4;
  int* ssrc   = (int*)ws;              ws += (size_t)NE * 4;
  int* flag   = (int*)ws;              ws += 256;

  // ---- CSR build ----
  detect_i64_kernel<<<1, 64, 0, stream>>>((const unsigned*)ei, flag);
  hipMemsetAsync(counts, 0, (size_t)NN * 4, stream);
  count_kernel<<<(NE + 255) / 256, 256, 0, stream>>>(ei, flag, counts);
  scan_kernel<<<1, 1024, 0, stream>>>(counts, rs);
  hipMemsetAsync(counts, 0, (size_t)NN * 4, stream);
  scatter_kernel<<<(NE + 255) / 256, 256, 0, stream>>>(ei, flag, rs, counts, ssrc);

  // ---- weight prep ----
  convert_wt_kernel<<<(256 * 256 + 255) / 256, 256, 0, stream>>>(W1, W1t, 256, 256 * 256);
  convert_wt_kernel<<<(128 * 256 + 255) / 256, 256, 0, stream>>>(W2, W2t, 128, 128 * 256);

  const int ngrid = (NN + 63) / 64;  // 782
  // ---- layer 1 ----
  gemm_mfma<256, 4, false><<<ngrid, 256, 0, stream>>>(x, W1t, hh, NN);
  alpha_kernel<32><<<(NN * 8 + 255) / 256, 256, 0, stream>>>(hh, aS1, aD1, alS, alD);
  agg1_kernel<<<(NN + 3) / 4, 256, 0, stream>>>(hh, alS, alD, rs, ssrc, b1, hmid);

  // ---- layer 2 ----
  gemm_mfma<128, 2, true><<<ngrid, 256, 0, stream>>>(hmid, W2t, hh, NN);
  alpha_kernel<16><<<(NN * 8 + 255) / 256, 256, 0, stream>>>(hh, aS2, aD2, alS, alD);
  agg2_kernel<<<(NN + 3) / 4, 256, 0, stream>>>(hh, alS, alD, rs, ssrc, b2, out);
}

// Round 5
// 319.700 us; speedup vs baseline: 1.7719x; 1.0556x over previous
//
#include <hip/hip_runtime.h>
#include <hip/hip_fp16.h>

#define NN 50000
#define NE 800000

typedef _Float16 half4v __attribute__((ext_vector_type(4)));
typedef _Float16 half8v __attribute__((ext_vector_type(8)));
typedef float f32x4 __attribute__((ext_vector_type(4)));

static __device__ __forceinline__ float lrelu(float x) { return x > 0.f ? x : 0.2f * x; }

// ---------------- edge-index dtype detection (int32 vs int64) ----------------
__global__ void detect_i64_kernel(const unsigned* __restrict__ ei, int* __restrict__ flag) {
  if (threadIdx.x == 0 && blockIdx.x == 0) {
    int is64 = 1;
    for (int i = 0; i < 64; ++i)
      if (ei[2 * i + 1] != 0u) { is64 = 0; break; }
    *flag = is64;
  }
}

static __device__ __forceinline__ int edge_at(const void* ei, int is64, long long idx) {
  if (is64) return (int)((const long long*)ei)[idx];
  return ((const int*)ei)[idx];
}

// ---------------- CSR build ----------------
__global__ void count_kernel(const void* __restrict__ ei, const int* __restrict__ flag,
                             int* __restrict__ counts) {
  int e = blockIdx.x * blockDim.x + threadIdx.x;
  if (e >= NE) return;
  int is64 = *flag;
  int d = edge_at(ei, is64, (long long)NE + e);
  atomicAdd(&counts[d], 1);
}

__global__ void scan_kernel(const int* __restrict__ counts, int* __restrict__ rs) {
  __shared__ int wsum[16];
  __shared__ int carry;
  const int tid = threadIdx.x;
  const int lane = tid & 63, wv = tid >> 6;
  if (tid == 0) { carry = 0; rs[0] = 0; }
  __syncthreads();
  for (int base = 0; base < NN; base += 1024) {
    int i = base + tid;
    int v = (i < NN) ? counts[i] : 0;
    #pragma unroll
    for (int off = 1; off < 64; off <<= 1) {
      int t = __shfl_up(v, off);
      if (lane >= off) v += t;
    }
    if (lane == 63) wsum[wv] = v;
    __syncthreads();
    if (tid == 0) {
      int run = 0;
      #pragma unroll
      for (int j = 0; j < 16; ++j) { run += wsum[j]; wsum[j] = run; }
    }
    __syncthreads();
    int add = carry + (wv ? wsum[wv - 1] : 0);
    if (i < NN) rs[i + 1] = add + v;
    __syncthreads();
    if (tid == 0) carry += wsum[15];
    __syncthreads();
  }
}

__global__ void scatter_kernel(const void* __restrict__ ei, const int* __restrict__ flag,
                               const int* __restrict__ rs, int* __restrict__ cursor,
                               int* __restrict__ ssrc) {
  int e = blockIdx.x * blockDim.x + threadIdx.x;
  if (e >= NE) return;
  int is64 = *flag;
  int s = edge_at(ei, is64, e);
  int d = edge_at(ei, is64, (long long)NE + e);
  int p = atomicAdd(&cursor[d], 1);
  ssrc[rs[d] + p] = s;
}

// ---------------- weight transpose + fp16 convert: Wt[n][k] = W[k][n], K=256 --
__global__ void convert_wt_kernel(const float* __restrict__ W, _Float16* __restrict__ Wt,
                                  int N, int total) {
  int i = blockIdx.x * blockDim.x + threadIdx.x;
  if (i >= total) return;
  int n = i >> 8, k = i & 255;
  Wt[i] = (_Float16)W[(size_t)k * N + n];
}

// ---------------- MFMA fp16 GEMM: C[M,BN] = A[M,256] @ Wt^T ------------------
template<int BN, int NCF, bool A_HALF>
__global__ __launch_bounds__(256) void gemm_mfma(const void* __restrict__ Araw,
                                                 const _Float16* __restrict__ Wt,
                                                 __half* __restrict__ C, int M) {
  __shared__ _Float16 As[64][256 + 8];
  const int tid = threadIdx.x;
  const int bm0 = blockIdx.x * 64;
  if (A_HALF) {
    const _Float16* A = (const _Float16*)Araw;
    for (int idx = tid; idx < 64 * 32; idx += 256) {
      int r = idx >> 5, c8 = (idx & 31) << 3;
      int gr = bm0 + r;
      half8v v = {};
      if (gr < M) v = *(const half8v*)&A[(size_t)gr * 256 + c8];
      *(half8v*)&As[r][c8] = v;
    }
  } else {
    const float* A = (const float*)Araw;
    for (int idx = tid; idx < 64 * 64; idx += 256) {
      int r = idx >> 6, c4 = (idx & 63) << 2;
      int gr = bm0 + r;
      float4 v = make_float4(0.f, 0.f, 0.f, 0.f);
      if (gr < M) v = *(const float4*)&A[(size_t)gr * 256 + c4];
      half4v h = { (_Float16)v.x, (_Float16)v.y, (_Float16)v.z, (_Float16)v.w };
      *(half4v*)&As[r][c4] = h;
    }
  }
  __syncthreads();
  const int lane = tid & 63, wv = tid >> 6;
  const int ncol0 = wv * (16 * NCF);
  const int lrow = lane & 15, lk8 = (lane >> 4) << 3;
  f32x4 acc[4][NCF];
  #pragma unroll
  for (int rf = 0; rf < 4; ++rf)
    #pragma unroll
    for (int cf = 0; cf < NCF; ++cf) acc[rf][cf] = (f32x4){0.f, 0.f, 0.f, 0.f};
  #pragma unroll
  for (int k0 = 0; k0 < 256; k0 += 32) {
    const int ks = k0 + lk8;
    half8v af[4];
    #pragma unroll
    for (int rf = 0; rf < 4; ++rf)
      af[rf] = *(const half8v*)&As[16 * rf + lrow][ks];
    #pragma unroll
    for (int cf = 0; cf < NCF; ++cf) {
      half8v bf = *(const half8v*)&Wt[(size_t)(ncol0 + 16 * cf + lrow) * 256 + ks];
      #pragma unroll
      for (int rf = 0; rf < 4; ++rf)
        acc[rf][cf] = __builtin_amdgcn_mfma_f32_16x16x32_f16(af[rf], bf, acc[rf][cf], 0, 0, 0);
    }
  }
  #pragma unroll
  for (int rf = 0; rf < 4; ++rf) {
    #pragma unroll
    for (int j = 0; j < 4; ++j) {
      int row = bm0 + 16 * rf + 4 * (lane >> 4) + j;
      if (row < M) {
        #pragma unroll
        for (int cf = 0; cf < NCF; ++cf) {
          int col = ncol0 + 16 * cf + lrow;
          C[(size_t)row * BN + col] = __float2half(acc[rf][cf][j]);
        }
      }
    }
  }
}

// ---------------- per-(node,head) attention coefficients (fp16 h) ----------
template<int C>
__global__ void alpha_kernel(const __half* __restrict__ h, const float* __restrict__ aws,
                             const float* __restrict__ awd, float* __restrict__ os,
                             float* __restrict__ od) {
  int i = blockIdx.x * blockDim.x + threadIdx.x;
  if (i >= NN * 8) return;
  int node = i >> 3, head = i & 7;
  const __half2* hp = (const __half2*)(h + (size_t)node * (8 * C) + head * C);
  const float* pws = aws + head * C;
  const float* pwd = awd + head * C;
  float s = 0.f, d = 0.f;
  #pragma unroll
  for (int c = 0; c < C / 2; ++c) {
    float2 v = __half22float2(hp[c]);
    s += v.x * pws[2 * c] + v.y * pws[2 * c + 1];
    d += v.x * pwd[2 * c] + v.y * pwd[2 * c + 1];
  }
  os[i] = s; od[i] = d;
}

// ---------------- layer-1 aggregation (fp16 h): softmax + sum + bias + ELU --
// one wave per node; no max-pass (logits are small: exp() safe in fp32);
// packed-fp16 accumulate, 4-deep pipelined edge loop.
__global__ __launch_bounds__(256) void agg1_kernel(const __half* __restrict__ h,
    const float* __restrict__ as, const float* __restrict__ ad,
    const int* __restrict__ rs, const int* __restrict__ ssrc,
    const float* __restrict__ bias, __half* __restrict__ out) {
  const int wid = (blockIdx.x * blockDim.x + threadIdx.x) >> 6;
  const int lane = threadIdx.x & 63;
  if (wid >= NN) return;
  const int node = wid;
  const int beg = rs[node], end = rs[node + 1];
  const int hd = lane >> 3;
  const float advh = ad[node * 8 + hd];
  float denom;
  __half2 acc01, acc23;
  {
    float p = __expf(lrelu(as[node * 8 + hd] + advh));   // self loop
    union { float2 f; __half2 q[2]; } u;
    u.f = *(const float2*)&h[(size_t)node * 256 + lane * 4];
    __half2 ph = __float2half2_rn(p);
    acc01 = __hmul2(ph, u.q[0]);
    acc23 = __hmul2(ph, u.q[1]);
    denom = p;
  }
  int it = beg;
  for (; it + 4 <= end; it += 4) {
    int s0 = ssrc[it], s1 = ssrc[it + 1], s2 = ssrc[it + 2], s3 = ssrc[it + 3];
    float b0 = as[s0 * 8 + hd], b1 = as[s1 * 8 + hd],
          b2 = as[s2 * 8 + hd], b3 = as[s3 * 8 + hd];
    union { float2 f; __half2 q[2]; } u0, u1, u2, u3;
    u0.f = *(const float2*)&h[(size_t)s0 * 256 + lane * 4];
    u1.f = *(const float2*)&h[(size_t)s1 * 256 + lane * 4];
    u2.f = *(const float2*)&h[(size_t)s2 * 256 + lane * 4];
    u3.f = *(const float2*)&h[(size_t)s3 * 256 + lane * 4];
    float p0 = __expf(lrelu(b0 + advh));
    float p1 = __expf(lrelu(b1 + advh));
    float p2 = __expf(lrelu(b2 + advh));
    float p3 = __expf(lrelu(b3 + advh));
    denom += p0 + p1 + p2 + p3;
    __half2 ph;
    ph = __float2half2_rn(p0);
    acc01 = __hfma2(ph, u0.q[0], acc01); acc23 = __hfma2(ph, u0.q[1], acc23);
    ph = __float2half2_rn(p1);
    acc01 = __hfma2(ph, u1.q[0], acc01); acc23 = __hfma2(ph, u1.q[1], acc23);
    ph = __float2half2_rn(p2);
    acc01 = __hfma2(ph, u2.q[0], acc01); acc23 = __hfma2(ph, u2.q[1], acc23);
    ph = __float2half2_rn(p3);
    acc01 = __hfma2(ph, u3.q[0], acc01); acc23 = __hfma2(ph, u3.q[1], acc23);
  }
  for (; it < end; ++it) {
    int s = ssrc[it];
    float p = __expf(lrelu(as[s * 8 + hd] + advh));
    union { float2 f; __half2 q[2]; } u;
    u.f = *(const float2*)&h[(size_t)s * 256 + lane * 4];
    __half2 ph = __float2half2_rn(p);
    acc01 = __hfma2(ph, u.q[0], acc01);
    acc23 = __hfma2(ph, u.q[1], acc23);
    denom += p;
  }
  const float inv = 1.f / (denom + 1e-16f);
  float2 a01 = __half22float2(acc01);
  float2 a23 = __half22float2(acc23);
  const float4 bv = *(const float4*)&bias[lane * 4];
  float4 o;
  o.x = a01.x * inv + bv.x; o.y = a01.y * inv + bv.y;
  o.z = a23.x * inv + bv.z; o.w = a23.y * inv + bv.w;
  o.x = o.x > 0.f ? o.x : __expf(o.x) - 1.f;
  o.y = o.y > 0.f ? o.y : __expf(o.y) - 1.f;
  o.z = o.z > 0.f ? o.z : __expf(o.z) - 1.f;
  o.w = o.w > 0.f ? o.w : __expf(o.w) - 1.f;
  union { __half2 h2[2]; float2 f2; } u;
  u.h2[0] = __floats2half2_rn(o.x, o.y);
  u.h2[1] = __floats2half2_rn(o.z, o.w);
  *(float2*)&out[(size_t)node * 256 + lane * 4] = u.f2;
}

// ---------------- layer-2 aggregation (fp16 h) + bias + log_softmax --------
// one wave per node; no max-pass; packed-fp16 accumulate.
__global__ __launch_bounds__(256) void agg2_kernel(const __half* __restrict__ h,
    const float* __restrict__ as, const float* __restrict__ ad,
    const int* __restrict__ rs, const int* __restrict__ ssrc,
    const float* __restrict__ bias, float* __restrict__ out) {
  const int wid = (blockIdx.x * blockDim.x + threadIdx.x) >> 6;
  const int lane = threadIdx.x & 63;
  if (wid >= NN) return;
  const int node = wid;
  const int beg = rs[node], end = rs[node + 1];
  const int hd = lane >> 3;
  const float advh = ad[node * 8 + hd];
  float denom;
  __half2 acc;
  {
    float p = __expf(lrelu(as[node * 8 + hd] + advh));   // self loop
    __half2 q = ((const __half2*)&h[(size_t)node * 128])[lane];
    acc = __hmul2(__float2half2_rn(p), q);
    denom = p;
  }
  int it = beg;
  for (; it + 4 <= end; it += 4) {
    int s0 = ssrc[it], s1 = ssrc[it + 1], s2 = ssrc[it + 2], s3 = ssrc[it + 3];
    float b0 = as[s0 * 8 + hd], b1 = as[s1 * 8 + hd],
          b2 = as[s2 * 8 + hd], b3 = as[s3 * 8 + hd];
    __half2 q0 = ((const __half2*)&h[(size_t)s0 * 128])[lane];
    __half2 q1 = ((const __half2*)&h[(size_t)s1 * 128])[lane];
    __half2 q2 = ((const __half2*)&h[(size_t)s2 * 128])[lane];
    __half2 q3 = ((const __half2*)&h[(size_t)s3 * 128])[lane];
    float p0 = __expf(lrelu(b0 + advh));
    float p1 = __expf(lrelu(b1 + advh));
    float p2 = __expf(lrelu(b2 + advh));
    float p3 = __expf(lrelu(b3 + advh));
    denom += p0 + p1 + p2 + p3;
    acc = __hfma2(__float2half2_rn(p0), q0, acc);
    acc = __hfma2(__float2half2_rn(p1), q1, acc);
    acc = __hfma2(__float2half2_rn(p2), q2, acc);
    acc = __hfma2(__float2half2_rn(p3), q3, acc);
  }
  for (; it < end; ++it) {
    int s = ssrc[it];
    float p = __expf(lrelu(as[s * 8 + hd] + advh));
    __half2 q = ((const __half2*)&h[(size_t)s * 128])[lane];
    acc = __hfma2(__float2half2_rn(p), q, acc);
    denom += p;
  }
  const float inv = 1.f / (denom + 1e-16f);
  float2 av = __half22float2(acc);
  float v0 = av.x * inv + bias[lane * 2 + 0];
  float v1 = av.y * inv + bias[lane * 2 + 1];
  float mx = fmaxf(v0, v1);
  #pragma unroll
  for (int off = 1; off < 64; off <<= 1) mx = fmaxf(mx, __shfl_xor(mx, off));
  float sum = __expf(v0 - mx) + __expf(v1 - mx);
  #pragma unroll
  for (int off = 1; off < 64; off <<= 1) sum += __shfl_xor(sum, off);
  float lse = mx + __logf(sum);
  float2 o = make_float2(v0 - lse, v1 - lse);
  __builtin_nontemporal_store(o.x, &out[(size_t)node * 128 + lane * 2]);
  __builtin_nontemporal_store(o.y, &out[(size_t)node * 128 + lane * 2 + 1]);
}

// ---------------- host ----------------
extern "C" void kernel_launch(void* const* d_in, const int* in_sizes, int n_in,
                              void* d_out, int out_size, void* d_ws, size_t ws_size,
                              hipStream_t stream) {
  const float* x    = (const float*)d_in[0];
  const void*  ei   = d_in[1];
  const float* W1   = (const float*)d_in[2];
  const float* aS1  = (const float*)d_in[3];
  const float* aD1  = (const float*)d_in[4];
  const float* b1   = (const float*)d_in[5];
  const float* W2   = (const float*)d_in[6];
  const float* aS2  = (const float*)d_in[7];
  const float* aD2  = (const float*)d_in[8];
  const float* b2   = (const float*)d_in[9];
  float* out = (float*)d_out;

  char* ws = (char*)d_ws;
  __half* hh   = (__half*)ws;          ws += (size_t)NN * 256 * 2;  // h (layer1) / h2 (layer2)
  __half* hmid = (__half*)ws;          ws += (size_t)NN * 256 * 2;  // ELU(agg1) fp16
  _Float16* W1t = (_Float16*)ws;       ws += (size_t)256 * 256 * 2; // [N=256][K=256]
  _Float16* W2t = (_Float16*)ws;       ws += (size_t)128 * 256 * 2; // [N=128][K=256]
  float* alS  = (float*)ws;            ws += (size_t)NN * 8 * 4;
  float* alD  = (float*)ws;            ws += (size_t)NN * 8 * 4;
  int* counts = (int*)ws;              ws += (size_t)NN * 4;
  int* rs     = (int*)ws;              ws += (size_t)(NN + 1) * 4;
  int* ssrc   = (int*)ws;              ws += (size_t)NE * 4;
  int* flag   = (int*)ws;              ws += 256;

  // ---- CSR build ----
  detect_i64_kernel<<<1, 64, 0, stream>>>((const unsigned*)ei, flag);
  hipMemsetAsync(counts, 0, (size_t)NN * 4, stream);
  count_kernel<<<(NE + 255) / 256, 256, 0, stream>>>(ei, flag, counts);
  scan_kernel<<<1, 1024, 0, stream>>>(counts, rs);
  hipMemsetAsync(counts, 0, (size_t)NN * 4, stream);
  scatter_kernel<<<(NE + 255) / 256, 256, 0, stream>>>(ei, flag, rs, counts, ssrc);

  // ---- weight prep ----
  convert_wt_kernel<<<(256 * 256 + 255) / 256, 256, 0, stream>>>(W1, W1t, 256, 256 * 256);
  convert_wt_kernel<<<(128 * 256 + 255) / 256, 256, 0, stream>>>(W2, W2t, 128, 128 * 256);

  const int ngrid = (NN + 63) / 64;  // 782
  // ---- layer 1 ----
  gemm_mfma<256, 4, false><<<ngrid, 256, 0, stream>>>(x, W1t, hh, NN);
  alpha_kernel<32><<<(NN * 8 + 255) / 256, 256, 0, stream>>>(hh, aS1, aD1, alS, alD);
  agg1_kernel<<<(NN + 3) / 4, 256, 0, stream>>>(hh, alS, alD, rs, ssrc, b1, hmid);

  // ---- layer 2 ----
  gemm_mfma<128, 2, true><<<ngrid, 256, 0, stream>>>(hmid, W2t, hh, NN);
  alpha_kernel<16><<<(NN * 8 + 255) / 256, 256, 0, stream>>>(hh, aS2, aD2, alS, alD);
  agg2_kernel<<<(NN + 3) / 4, 256, 0, stream>>>(hh, alS, alD, rs, ssrc, b2, out);
}